// Round 9
// baseline (299.094 us; speedup 1.0000x reference)
//
#include <hip/hip_runtime.h>
#include <math.h>

typedef __attribute__((ext_vector_type(8))) short short8;
typedef __attribute__((ext_vector_type(4))) short short4v;
typedef __attribute__((ext_vector_type(4))) float floatx4;

#define AS1 __attribute__((address_space(1)))
#define AS3 __attribute__((address_space(3)))

__device__ inline void gload_lds16(const short* g, short* l) {
    __builtin_amdgcn_global_load_lds((const AS1 unsigned int*)g,
                                     (AS3 unsigned int*)l, 16, 0, 0);
}

__device__ inline short f2bf(float f) {
    unsigned u = __builtin_bit_cast(unsigned, f);
    u += 0x7fffu + ((u >> 16) & 1u);
    return (short)(u >> 16);
}

// ---------------------------------------------------------------------------
// x [8M] fp32 -> bf16
// ---------------------------------------------------------------------------
__global__ __launch_bounds__(256) void conv_x(
    const float* __restrict__ x, short* __restrict__ xb)
{
    int i = (blockIdx.x * 256 + threadIdx.x) * 4;
    float4 v = *(const float4*)&x[i];
    short4v o = { f2bf(v.x), f2bf(v.y), f2bf(v.z), f2bf(v.w) };
    *(short4v*)&xb[i] = o;
}

// ---------------------------------------------------------------------------
// Coalesced weight transpose + fp32->bf16 via 64x64 LDS tiles.
// Wall [3072,1024]: rows 0-1023 = Wq^T * (0.125*log2e)  [exp2-folded scale],
//                   1024-2047 = Wk^T, 2048-3071 = Wv^T.
// WoT [1024,1024] = Wo^T.  Grid (16 k-tiles, 16 slices).
// ---------------------------------------------------------------------------
__global__ __launch_bounds__(256) void transpose_w(
    const float* __restrict__ Wq, const float* __restrict__ Wk,
    const float* __restrict__ Wv, const float* __restrict__ Wo,
    short* __restrict__ Wall, short* __restrict__ WoT)
{
    __shared__ short T[64 * 72];
    const int kt = blockIdx.x, y = blockIdx.y;
    const int tid = threadIdx.x;
    const int lr = tid >> 2, lc = (tid & 3) * 16;
    #pragma unroll 1
    for (int m = 0; m < 4; ++m) {
        const float* src;
        float s = 1.f;
        if (m < 3) {
            const float* W = (m == 0) ? Wq : (m == 1) ? Wk : Wv;
            src = W + ((size_t)y << 16) + (size_t)(kt * 64 + lr) * 64 + lc;
            if (m == 0) s = 0.125f * 1.44269504088896f;   // 1/sqrt(D) * log2(e)
        } else {
            src = Wo + (size_t)(kt * 64 + lr) * 1024 + y * 64 + lc;
        }
        short8 t0, t1;
        {
            float4 v0 = *(const float4*)(src + 0);
            float4 v1 = *(const float4*)(src + 4);
            float4 v2 = *(const float4*)(src + 8);
            float4 v3 = *(const float4*)(src + 12);
            t0[0]=f2bf(v0.x*s); t0[1]=f2bf(v0.y*s); t0[2]=f2bf(v0.z*s); t0[3]=f2bf(v0.w*s);
            t0[4]=f2bf(v1.x*s); t0[5]=f2bf(v1.y*s); t0[6]=f2bf(v1.z*s); t0[7]=f2bf(v1.w*s);
            t1[0]=f2bf(v2.x*s); t1[1]=f2bf(v2.y*s); t1[2]=f2bf(v2.z*s); t1[3]=f2bf(v2.w*s);
            t1[4]=f2bf(v3.x*s); t1[5]=f2bf(v3.y*s); t1[6]=f2bf(v3.z*s); t1[7]=f2bf(v3.w*s);
        }
        *(short8*)&T[lr * 72 + lc]     = t0;
        *(short8*)&T[lr * 72 + lc + 8] = t1;
        __syncthreads();
        short8 o0, o1;
        #pragma unroll
        for (int j = 0; j < 8; ++j) o0[j] = T[(lc + j) * 72 + lr];
        #pragma unroll
        for (int j = 0; j < 8; ++j) o1[j] = T[(lc + 8 + j) * 72 + lr];
        short* dst = (m < 3)
            ? Wall + (size_t)(m * 1024 + y * 64 + lr) * 1024 + kt * 64
            : WoT  + (size_t)(y * 64 + lr) * 1024 + kt * 64;
        *(short8*)&dst[lc]     = o0;
        *(short8*)&dst[lc + 8] = o1;
        __syncthreads();
    }
}

// ---------------------------------------------------------------------------
// V [B*T, 1024] bf16 (col = h*64+d)  ->  Vt_g [b*16+h][d=64][t=2048] bf16.
// ---------------------------------------------------------------------------
__global__ __launch_bounds__(256) void transpose_v(
    const short* __restrict__ Vp, short* __restrict__ Vt_g)
{
    __shared__ short T[64 * 72];
    const int t0 = blockIdx.x * 64;
    const int h = blockIdx.y, b = blockIdx.z;
    const int tid = threadIdx.x;
    const int r = tid >> 3, c = (tid & 7) * 8;
    #pragma unroll
    for (int p = 0; p < 2; ++p) {
        int t = r + 32 * p;
        *(short8*)&T[t * 72 + c] =
            *(const short8*)&Vp[(size_t)(b * 2048 + t0 + t) * 1024 + h * 64 + c];
    }
    __syncthreads();
    const int d = tid >> 2, tc = (tid & 3) * 16;
    size_t obase = ((size_t)(b * 16 + h)) * 64 * 2048 + (size_t)d * 2048 + t0 + tc;
    short8 o0, o1;
    #pragma unroll
    for (int j = 0; j < 8; ++j) o0[j] = T[(tc + j) * 72 + d];
    #pragma unroll
    for (int j = 0; j < 8; ++j) o1[j] = T[(tc + 8 + j) * 72 + d];
    *(short8*)&Vt_g[obase] = o0;
    *(short8*)&Vt_g[obase + 8] = o1;
}

// ---------------------------------------------------------------------------
// C = A[M,K] @ BT[N,K]^T (+bias), bf16 in, fp32 accum.
// split=1 (QKV): plane = col>>10; plane 0 -> C (Q), 1 -> C+8M (K), 2 -> Cv (V).
// ---------------------------------------------------------------------------
__global__ __launch_bounds__(256) void gemm_bt(
    const short* __restrict__ A, const short* __restrict__ BT,
    short* __restrict__ C, short* __restrict__ Cv, float* __restrict__ Cf,
    const float* __restrict__ bias, int M, int N, int K, int split)
{
    __shared__ short As[128 * 32];
    __shared__ short Bs[128 * 32];
    const int tid  = threadIdx.x;
    const int wid  = tid >> 6, lane = tid & 63;
    const int quad = lane >> 4, l15 = lane & 15;
    const int m0 = blockIdx.x * 128, n0 = blockIdx.y * 128;
    const int wr = (wid >> 1) * 64, wc = (wid & 1) * 64;

    floatx4 acc[4][4] = {};

    const int srow = wid * 32 + (lane >> 2);
    const int scol = (lane & 3) * 8;

    for (int k0 = 0; k0 < K; k0 += 32) {
        #pragma unroll
        for (int t = 0; t < 2; ++t) {
            gload_lds16(A  + (size_t)(m0 + srow + t * 16) * K + k0 + scol,
                        &As[(wid * 32 + t * 16) * 32]);
            gload_lds16(BT + (size_t)(n0 + srow + t * 16) * K + k0 + scol,
                        &Bs[(wid * 32 + t * 16) * 32]);
        }
        __syncthreads();
        short8 bfr[4];
        #pragma unroll
        for (int j = 0; j < 4; ++j)
            bfr[j] = *(const short8*)&Bs[(wc + j * 16 + l15) * 32 + quad * 8];
        #pragma unroll
        for (int i = 0; i < 4; ++i) {
            short8 afr = *(const short8*)&As[(wr + i * 16 + l15) * 32 + quad * 8];
            #pragma unroll
            for (int j = 0; j < 4; ++j)
                acc[i][j] = __builtin_amdgcn_mfma_f32_16x16x32_bf16(
                    afr, bfr[j], acc[i][j], 0, 0, 0);
        }
        __syncthreads();
    }

    #pragma unroll
    for (int i = 0; i < 4; ++i) {
        int row = m0 + wr + i * 16 + quad * 4;
        #pragma unroll
        for (int j = 0; j < 4; ++j) {
            int col = n0 + wc + j * 16 + l15;
            if (Cf) {
                float bv = bias ? bias[col] : 0.f;
                #pragma unroll
                for (int r = 0; r < 4; ++r)
                    Cf[(size_t)(row + r) * N + col] = acc[i][j][r] + bv;
            } else if (split) {
                int plane = col >> 10, c1 = col & 1023;
                short* dst = (plane == 2) ? Cv
                           : C + (size_t)plane * 8192 * 1024;
                #pragma unroll
                for (int r = 0; r < 4; ++r)
                    dst[(size_t)(row + r) * 1024 + c1] = f2bf(acc[i][j][r]);
            } else {
                #pragma unroll
                for (int r = 0; r < 4; ++r)
                    C[(size_t)(row + r) * 1024 + col] = f2bf(acc[i][j][r]);
            }
        }
    }
}

// ---------------------------------------------------------------------------
// Flash attention, causal, non-online softmax. Q pre-scaled by log2e/sqrt(D)
// (exp2-folded) -> scores exponentiated with native exp2f.
// Row-sums l computed by MFMA against a constant all-ones B operand held in
// registers (no VALU adds, no end-of-phase shuffle reduce; result lands
// pre-reduced in the same [mt][r] lanes the epilogue divides in).
// Block = 128 q-rows, 4 waves x 32 rows. Grid (8,H,B): block pi does q-tiles
// {15-pi, pi} -> uniform 34 s-iters. Double-buffered K/V LDS, 1 barrier/iter,
// register prefetch 2 tiles ahead with incremental pointers.
// ---------------------------------------------------------------------------
__global__ __launch_bounds__(256) void attn_fwd(
    const short* __restrict__ Q, const short* __restrict__ Kg,
    const short* __restrict__ Vt_g, short* __restrict__ O)
{
    __shared__ short Ks[2][64 * 72];
    __shared__ short Vs[2][64 * 72];
    __shared__ short Pb[4 * 32 * 72];
    const int tid  = threadIdx.x;
    const int wid  = tid >> 6, lane = tid & 63;
    const int quad = lane >> 4, l15 = lane & 15;
    const int pi = blockIdx.x, h = blockIdx.y, b = blockIdx.z;
    const size_t base  = ((size_t)b * 2048) * 1024 + h * 64;
    const size_t vbase = ((size_t)(b * 16 + h)) * 64 * 2048;
    const int sr = tid >> 3, sc = (tid & 7) * 8;
    short* Pw = &Pb[wid * 32 * 72];

    const short one_bf = (short)0x3F80;          // bf16 1.0
    const short8 bones = { one_bf, one_bf, one_bf, one_bf,
                           one_bf, one_bf, one_bf, one_bf };

    for (int ph = 0; ph < 2; ++ph) {
        const int qt = ph ? pi : 15 - pi;
        short8 qf[2][2];
        #pragma unroll
        for (int mt = 0; mt < 2; ++mt)
            #pragma unroll
            for (int ks = 0; ks < 2; ++ks)
                qf[mt][ks] = *(const short8*)&Q[base +
                    (size_t)(qt * 128 + wid * 32 + mt * 16 + l15) * 1024 + ks * 32 + quad * 8];

        floatx4 oacc[2][4] = {};
        floatx4 lacc[2] = {};
        const int dst = 2 * qt + (wid >> 1);
        const int nst = 2 * qt + 2;

        // incremental global pointers (per-lane bases, constant strides)
        const short* kcur = Kg + base + (size_t)sr * 1024 + sc;
        const short* vcur = Vt_g + vbase + (size_t)sr * 2048 + sc;

        // prologue: tile0 -> regs -> buf0; tile1 -> regs
        short8 kv[2], vv[2];
        #pragma unroll
        for (int p = 0; p < 2; ++p) {
            kv[p] = *(const short8*)(kcur + (size_t)p * 32 * 1024);
            vv[p] = *(const short8*)(vcur + (size_t)p * 32 * 2048);
        }
        kcur += 64 * 1024; vcur += 64;
        #pragma unroll
        for (int p = 0; p < 2; ++p) {
            int row = sr + 32 * p;
            *(short8*)&Ks[0][row * 72 + sc] = kv[p];
            *(short8*)&Vs[0][row * 72 + sc] = vv[p];
        }
        #pragma unroll
        for (int p = 0; p < 2; ++p) {
            kv[p] = *(const short8*)(kcur + (size_t)p * 32 * 1024);
            vv[p] = *(const short8*)(vcur + (size_t)p * 32 * 2048);
        }
        kcur += 64 * 1024; vcur += 64;
        __syncthreads();

        for (int st = 0; st < nst; ++st) {
            const short* K0 = Ks[st & 1];
            const short* V0 = Vs[st & 1];
            if (st + 1 < nst) {
                short* K1 = Ks[(st + 1) & 1];
                short* V1 = Vs[(st + 1) & 1];
                #pragma unroll
                for (int p = 0; p < 2; ++p) {
                    int row = sr + 32 * p;
                    *(short8*)&K1[row * 72 + sc] = kv[p];
                    *(short8*)&V1[row * 72 + sc] = vv[p];
                }
            }
            if (st + 2 < nst) {
                #pragma unroll
                for (int p = 0; p < 2; ++p) {
                    kv[p] = *(const short8*)(kcur + (size_t)p * 32 * 1024);
                    vv[p] = *(const short8*)(vcur + (size_t)p * 32 * 2048);
                }
                kcur += 64 * 1024; vcur += 64;
            }

            if (st <= dst) {
                floatx4 sf[2][4];
                #pragma unroll
                for (int nt = 0; nt < 4; ++nt) {
                    floatx4 z0 = {}, z1 = {};
                    #pragma unroll
                    for (int ks = 0; ks < 2; ++ks) {
                        short8 bfr = *(const short8*)&K0[(nt * 16 + l15) * 72 + ks * 32 + quad * 8];
                        z0 = __builtin_amdgcn_mfma_f32_16x16x32_bf16(qf[0][ks], bfr, z0, 0, 0, 0);
                        z1 = __builtin_amdgcn_mfma_f32_16x16x32_bf16(qf[1][ks], bfr, z1, 0, 0, 0);
                    }
                    sf[0][nt] = z0; sf[1][nt] = z1;
                }

                if (st == dst) {
                    #pragma unroll
                    for (int mt = 0; mt < 2; ++mt)
                        #pragma unroll
                        for (int nt = 0; nt < 4; ++nt)
                            #pragma unroll
                            for (int r = 0; r < 4; ++r) {
                                int qa = qt * 128 + wid * 32 + mt * 16 + quad * 4 + r;
                                int sa = st * 64 + nt * 16 + l15;
                                if (sa > qa) sf[mt][nt][r] = -INFINITY;
                            }
                }

                // p = 2^s (native exp); quantize round-half-up to bf16
                #pragma unroll
                for (int mt = 0; mt < 2; ++mt)
                    #pragma unroll
                    for (int nt = 0; nt < 4; ++nt)
                        #pragma unroll
                        for (int r = 0; r < 4; ++r) {
                            float p = exp2f(sf[mt][nt][r]);
                            unsigned u = __builtin_bit_cast(unsigned, p) + 0x8000u;
                            Pw[(mt * 16 + quad * 4 + r) * 72 + ((nt ^ quad) * 16) + l15] =
                                (short)(u >> 16);
                        }
                // no barrier: P is wave-private

                #pragma unroll
                for (int ks = 0; ks < 2; ++ks) {
                    int blk = (ks * 2 + (quad >> 1)) ^ (l15 >> 2);
                    short8 af0 = *(const short8*)&Pw[(l15) * 72 + blk * 16 + (quad & 1) * 8];
                    short8 af1 = *(const short8*)&Pw[(16 + l15) * 72 + blk * 16 + (quad & 1) * 8];
                    lacc[0] = __builtin_amdgcn_mfma_f32_16x16x32_bf16(af0, bones, lacc[0], 0, 0, 0);
                    lacc[1] = __builtin_amdgcn_mfma_f32_16x16x32_bf16(af1, bones, lacc[1], 0, 0, 0);
                    #pragma unroll
                    for (int nt = 0; nt < 4; ++nt) {
                        short8 bfr = *(const short8*)&V0[(nt * 16 + l15) * 72 + ks * 32 + quad * 8];
                        oacc[0][nt] = __builtin_amdgcn_mfma_f32_16x16x32_bf16(af0, bfr, oacc[0][nt], 0, 0, 0);
                        oacc[1][nt] = __builtin_amdgcn_mfma_f32_16x16x32_bf16(af1, bfr, oacc[1][nt], 0, 0, 0);
                    }
                }
            }
            __syncthreads();
        }

        // lacc[mt][r] already holds the full row-sum for row quad*4+r
        // (replicated across l15) — no reduction needed.
        #pragma unroll
        for (int mt = 0; mt < 2; ++mt)
            #pragma unroll
            for (int nt = 0; nt < 4; ++nt)
                #pragma unroll
                for (int r = 0; r < 4; ++r) {
                    float v = oacc[mt][nt][r] / lacc[mt][r];
                    int qa = qt * 128 + wid * 32 + mt * 16 + quad * 4 + r;
                    O[base + (size_t)qa * 1024 + nt * 16 + l15] = f2bf(v);
                }
    }
}

// ---------------------------------------------------------------------------
// Workspace (40 MB, proven):
//   ws[ 0..16): xb (QKV-gemm input) -> Vt_g (after QKV gemm)
//   ws[16..32): Vr (QKV gemm V-plane) -> Ao (after transpose_v)
//   ws[32..38): Wall = [Wq^T*c | Wk^T | Wv^T]   ws[38..40): WoT
//   d_out: Qp (lo 16MB) + Kp (hi 16MB); overwritten by final fp32 output.
// ---------------------------------------------------------------------------
extern "C" void kernel_launch(void* const* d_in, const int* in_sizes, int n_in,
                              void* d_out, int out_size, void* d_ws, size_t ws_size,
                              hipStream_t stream) {
    const float* x  = (const float*)d_in[0];
    const float* Wq = (const float*)d_in[1];
    const float* Wk = (const float*)d_in[2];
    const float* Wv = (const float*)d_in[3];
    const float* Wo = (const float*)d_in[4];
    const float* bo = (const float*)d_in[5];
    float* out = (float*)d_out;

    char* ws = (char*)d_ws;
    const size_t MB = 1024 * 1024;
    short* xb   = (short*)(ws + 0 * MB);
    short* Vt_g = (short*)(ws + 0 * MB);    // overlays xb (dead after QKV gemm)
    short* Vr   = (short*)(ws + 16 * MB);
    short* Ao   = (short*)(ws + 16 * MB);   // overlays Vr (dead after transpose_v)
    short* Wall = (short*)(ws + 32 * MB);
    short* WoT  = (short*)(ws + 38 * MB);
    short* Qp   = (short*)d_out;            // d_out lo
    short* Kp   = Qp + 8 * 1024 * 1024;     // d_out hi

    conv_x<<<8192, 256, 0, stream>>>(x, xb);
    transpose_w<<<dim3(16, 16), 256, 0, stream>>>(Wq, Wk, Wv, Wo, Wall, WoT);

    gemm_bt<<<dim3(64, 24), 256, 0, stream>>>(xb, Wall, Qp, Vr, nullptr, nullptr,
                                              8192, 3072, 1024, 1);
    transpose_v<<<dim3(32, 16, 4), 256, 0, stream>>>(Vr, Vt_g);

    attn_fwd<<<dim3(8, 16, 4), 256, 0, stream>>>(Qp, Kp, Vt_g, Ao);

    gemm_bt<<<dim3(64, 8), 256, 0, stream>>>(Ao, WoT, nullptr, nullptr, out, bo,
                                             8192, 1024, 1024, 0);
}

// Round 10
// 287.426 us; speedup vs baseline: 1.0406x; 1.0406x over previous
//
#include <hip/hip_runtime.h>
#include <math.h>

typedef __attribute__((ext_vector_type(8))) short short8;
typedef __attribute__((ext_vector_type(4))) short short4v;
typedef __attribute__((ext_vector_type(4))) float floatx4;

#define AS1 __attribute__((address_space(1)))
#define AS3 __attribute__((address_space(3)))

__device__ inline void gload_lds16(const short* g, short* l) {
    __builtin_amdgcn_global_load_lds((const AS1 unsigned int*)g,
                                     (AS3 unsigned int*)l, 16, 0, 0);
}

__device__ inline short f2bf(float f) {
    unsigned u = __builtin_bit_cast(unsigned, f);
    u += 0x7fffu + ((u >> 16) & 1u);
    return (short)(u >> 16);
}

// ---------------------------------------------------------------------------
// x [8M] fp32 -> bf16
// ---------------------------------------------------------------------------
__global__ __launch_bounds__(256) void conv_x(
    const float* __restrict__ x, short* __restrict__ xb)
{
    int i = (blockIdx.x * 256 + threadIdx.x) * 4;
    float4 v = *(const float4*)&x[i];
    short4v o = { f2bf(v.x), f2bf(v.y), f2bf(v.z), f2bf(v.w) };
    *(short4v*)&xb[i] = o;
}

// ---------------------------------------------------------------------------
// Coalesced weight transpose + fp32->bf16 via 64x64 LDS tiles.
// Wall [3072,1024]: rows 0-1023 = Wq^T * (0.125*log2e)  [exp2-folded scale],
//                   1024-2047 = Wk^T, 2048-3071 = Wv^T.
// WoT [1024,1024] = Wo^T.  Grid (16 k-tiles, 16 slices).
// ---------------------------------------------------------------------------
__global__ __launch_bounds__(256) void transpose_w(
    const float* __restrict__ Wq, const float* __restrict__ Wk,
    const float* __restrict__ Wv, const float* __restrict__ Wo,
    short* __restrict__ Wall, short* __restrict__ WoT)
{
    __shared__ short T[64 * 72];
    const int kt = blockIdx.x, y = blockIdx.y;
    const int tid = threadIdx.x;
    const int lr = tid >> 2, lc = (tid & 3) * 16;
    #pragma unroll 1
    for (int m = 0; m < 4; ++m) {
        const float* src;
        float s = 1.f;
        if (m < 3) {
            const float* W = (m == 0) ? Wq : (m == 1) ? Wk : Wv;
            src = W + ((size_t)y << 16) + (size_t)(kt * 64 + lr) * 64 + lc;
            if (m == 0) s = 0.125f * 1.44269504088896f;   // 1/sqrt(D) * log2(e)
        } else {
            src = Wo + (size_t)(kt * 64 + lr) * 1024 + y * 64 + lc;
        }
        short8 t0, t1;
        {
            float4 v0 = *(const float4*)(src + 0);
            float4 v1 = *(const float4*)(src + 4);
            float4 v2 = *(const float4*)(src + 8);
            float4 v3 = *(const float4*)(src + 12);
            t0[0]=f2bf(v0.x*s); t0[1]=f2bf(v0.y*s); t0[2]=f2bf(v0.z*s); t0[3]=f2bf(v0.w*s);
            t0[4]=f2bf(v1.x*s); t0[5]=f2bf(v1.y*s); t0[6]=f2bf(v1.z*s); t0[7]=f2bf(v1.w*s);
            t1[0]=f2bf(v2.x*s); t1[1]=f2bf(v2.y*s); t1[2]=f2bf(v2.z*s); t1[3]=f2bf(v2.w*s);
            t1[4]=f2bf(v3.x*s); t1[5]=f2bf(v3.y*s); t1[6]=f2bf(v3.z*s); t1[7]=f2bf(v3.w*s);
        }
        *(short8*)&T[lr * 72 + lc]     = t0;
        *(short8*)&T[lr * 72 + lc + 8] = t1;
        __syncthreads();
        short8 o0, o1;
        #pragma unroll
        for (int j = 0; j < 8; ++j) o0[j] = T[(lc + j) * 72 + lr];
        #pragma unroll
        for (int j = 0; j < 8; ++j) o1[j] = T[(lc + 8 + j) * 72 + lr];
        short* dst = (m < 3)
            ? Wall + (size_t)(m * 1024 + y * 64 + lr) * 1024 + kt * 64
            : WoT  + (size_t)(y * 64 + lr) * 1024 + kt * 64;
        *(short8*)&dst[lc]     = o0;
        *(short8*)&dst[lc + 8] = o1;
        __syncthreads();
    }
}

// ---------------------------------------------------------------------------
// V [B*T, 1024] bf16 (col = h*64+d)  ->  Vt_g [b*16+h][d=64][t=2048] bf16.
// ---------------------------------------------------------------------------
__global__ __launch_bounds__(256) void transpose_v(
    const short* __restrict__ Vp, short* __restrict__ Vt_g)
{
    __shared__ short T[64 * 72];
    const int t0 = blockIdx.x * 64;
    const int h = blockIdx.y, b = blockIdx.z;
    const int tid = threadIdx.x;
    const int r = tid >> 3, c = (tid & 7) * 8;
    #pragma unroll
    for (int p = 0; p < 2; ++p) {
        int t = r + 32 * p;
        *(short8*)&T[t * 72 + c] =
            *(const short8*)&Vp[(size_t)(b * 2048 + t0 + t) * 1024 + h * 64 + c];
    }
    __syncthreads();
    const int d = tid >> 2, tc = (tid & 3) * 16;
    size_t obase = ((size_t)(b * 16 + h)) * 64 * 2048 + (size_t)d * 2048 + t0 + tc;
    short8 o0, o1;
    #pragma unroll
    for (int j = 0; j < 8; ++j) o0[j] = T[(tc + j) * 72 + d];
    #pragma unroll
    for (int j = 0; j < 8; ++j) o1[j] = T[(tc + 8 + j) * 72 + d];
    *(short8*)&Vt_g[obase] = o0;
    *(short8*)&Vt_g[obase + 8] = o1;
}

// ---------------------------------------------------------------------------
// C = A[M,K] @ BT[N,K]^T (+bias), bf16 in, fp32 accum.
// split=1 (QKV): plane = col>>10; plane 0 -> C (Q), 1 -> C+8M (K), 2 -> Cv (V).
// ---------------------------------------------------------------------------
__global__ __launch_bounds__(256) void gemm_bt(
    const short* __restrict__ A, const short* __restrict__ BT,
    short* __restrict__ C, short* __restrict__ Cv, float* __restrict__ Cf,
    const float* __restrict__ bias, int M, int N, int K, int split)
{
    __shared__ short As[128 * 32];
    __shared__ short Bs[128 * 32];
    const int tid  = threadIdx.x;
    const int wid  = tid >> 6, lane = tid & 63;
    const int quad = lane >> 4, l15 = lane & 15;
    const int m0 = blockIdx.x * 128, n0 = blockIdx.y * 128;
    const int wr = (wid >> 1) * 64, wc = (wid & 1) * 64;

    floatx4 acc[4][4] = {};

    const int srow = wid * 32 + (lane >> 2);
    const int scol = (lane & 3) * 8;

    for (int k0 = 0; k0 < K; k0 += 32) {
        #pragma unroll
        for (int t = 0; t < 2; ++t) {
            gload_lds16(A  + (size_t)(m0 + srow + t * 16) * K + k0 + scol,
                        &As[(wid * 32 + t * 16) * 32]);
            gload_lds16(BT + (size_t)(n0 + srow + t * 16) * K + k0 + scol,
                        &Bs[(wid * 32 + t * 16) * 32]);
        }
        __syncthreads();
        short8 bfr[4];
        #pragma unroll
        for (int j = 0; j < 4; ++j)
            bfr[j] = *(const short8*)&Bs[(wc + j * 16 + l15) * 32 + quad * 8];
        #pragma unroll
        for (int i = 0; i < 4; ++i) {
            short8 afr = *(const short8*)&As[(wr + i * 16 + l15) * 32 + quad * 8];
            #pragma unroll
            for (int j = 0; j < 4; ++j)
                acc[i][j] = __builtin_amdgcn_mfma_f32_16x16x32_bf16(
                    afr, bfr[j], acc[i][j], 0, 0, 0);
        }
        __syncthreads();
    }

    #pragma unroll
    for (int i = 0; i < 4; ++i) {
        int row = m0 + wr + i * 16 + quad * 4;
        #pragma unroll
        for (int j = 0; j < 4; ++j) {
            int col = n0 + wc + j * 16 + l15;
            if (Cf) {
                float bv = bias ? bias[col] : 0.f;
                #pragma unroll
                for (int r = 0; r < 4; ++r)
                    Cf[(size_t)(row + r) * N + col] = acc[i][j][r] + bv;
            } else if (split) {
                int plane = col >> 10, c1 = col & 1023;
                short* dst = (plane == 2) ? Cv
                           : C + (size_t)plane * 8192 * 1024;
                #pragma unroll
                for (int r = 0; r < 4; ++r)
                    dst[(size_t)(row + r) * 1024 + c1] = f2bf(acc[i][j][r]);
            } else {
                #pragma unroll
                for (int r = 0; r < 4; ++r)
                    C[(size_t)(row + r) * 1024 + col] = f2bf(acc[i][j][r]);
            }
        }
    }
}

// ---------------------------------------------------------------------------
// Flash attention, causal, non-online softmax. Q pre-scaled by log2e/sqrt(D);
// exponentiation is a single raw v_exp_f32 (__builtin_amdgcn_exp2f) per
// element — no libm fixup code (the R9 regression), no multiply.
// Row-sums l via MFMA against an all-ones B operand held in registers.
// Block = 128 q-rows, 4 waves x 32 rows. Grid (8,H,B): block pi does q-tiles
// {15-pi, pi} -> uniform 34 s-iters. Double-buffered K/V LDS, 1 barrier/iter,
// register prefetch 2 tiles ahead with incremental pointers.
// ---------------------------------------------------------------------------
__global__ __launch_bounds__(256) void attn_fwd(
    const short* __restrict__ Q, const short* __restrict__ Kg,
    const short* __restrict__ Vt_g, short* __restrict__ O)
{
    __shared__ short Ks[2][64 * 72];
    __shared__ short Vs[2][64 * 72];
    __shared__ short Pb[4 * 32 * 72];
    const int tid  = threadIdx.x;
    const int wid  = tid >> 6, lane = tid & 63;
    const int quad = lane >> 4, l15 = lane & 15;
    const int pi = blockIdx.x, h = blockIdx.y, b = blockIdx.z;
    const size_t base  = ((size_t)b * 2048) * 1024 + h * 64;
    const size_t vbase = ((size_t)(b * 16 + h)) * 64 * 2048;
    const int sr = tid >> 3, sc = (tid & 7) * 8;
    short* Pw = &Pb[wid * 32 * 72];

    const short one_bf = (short)0x3F80;          // bf16 1.0
    const short8 bones = { one_bf, one_bf, one_bf, one_bf,
                           one_bf, one_bf, one_bf, one_bf };

    for (int ph = 0; ph < 2; ++ph) {
        const int qt = ph ? pi : 15 - pi;
        short8 qf[2][2];
        #pragma unroll
        for (int mt = 0; mt < 2; ++mt)
            #pragma unroll
            for (int ks = 0; ks < 2; ++ks)
                qf[mt][ks] = *(const short8*)&Q[base +
                    (size_t)(qt * 128 + wid * 32 + mt * 16 + l15) * 1024 + ks * 32 + quad * 8];

        floatx4 oacc[2][4] = {};
        floatx4 lacc[2] = {};
        const int dst = 2 * qt + (wid >> 1);
        const int nst = 2 * qt + 2;

        // incremental global pointers (per-lane bases, constant strides)
        const short* kcur = Kg + base + (size_t)sr * 1024 + sc;
        const short* vcur = Vt_g + vbase + (size_t)sr * 2048 + sc;

        // prologue: tile0 -> regs -> buf0; tile1 -> regs
        short8 kv[2], vv[2];
        #pragma unroll
        for (int p = 0; p < 2; ++p) {
            kv[p] = *(const short8*)(kcur + (size_t)p * 32 * 1024);
            vv[p] = *(const short8*)(vcur + (size_t)p * 32 * 2048);
        }
        kcur += 64 * 1024; vcur += 64;
        #pragma unroll
        for (int p = 0; p < 2; ++p) {
            int row = sr + 32 * p;
            *(short8*)&Ks[0][row * 72 + sc] = kv[p];
            *(short8*)&Vs[0][row * 72 + sc] = vv[p];
        }
        #pragma unroll
        for (int p = 0; p < 2; ++p) {
            kv[p] = *(const short8*)(kcur + (size_t)p * 32 * 1024);
            vv[p] = *(const short8*)(vcur + (size_t)p * 32 * 2048);
        }
        kcur += 64 * 1024; vcur += 64;
        __syncthreads();

        for (int st = 0; st < nst; ++st) {
            const short* K0 = Ks[st & 1];
            const short* V0 = Vs[st & 1];
            if (st + 1 < nst) {
                short* K1 = Ks[(st + 1) & 1];
                short* V1 = Vs[(st + 1) & 1];
                #pragma unroll
                for (int p = 0; p < 2; ++p) {
                    int row = sr + 32 * p;
                    *(short8*)&K1[row * 72 + sc] = kv[p];
                    *(short8*)&V1[row * 72 + sc] = vv[p];
                }
            }
            if (st + 2 < nst) {
                #pragma unroll
                for (int p = 0; p < 2; ++p) {
                    kv[p] = *(const short8*)(kcur + (size_t)p * 32 * 1024);
                    vv[p] = *(const short8*)(vcur + (size_t)p * 32 * 2048);
                }
                kcur += 64 * 1024; vcur += 64;
            }

            if (st <= dst) {
                floatx4 sf[2][4];
                #pragma unroll
                for (int nt = 0; nt < 4; ++nt) {
                    floatx4 z0 = {}, z1 = {};
                    #pragma unroll
                    for (int ks = 0; ks < 2; ++ks) {
                        short8 bfr = *(const short8*)&K0[(nt * 16 + l15) * 72 + ks * 32 + quad * 8];
                        z0 = __builtin_amdgcn_mfma_f32_16x16x32_bf16(qf[0][ks], bfr, z0, 0, 0, 0);
                        z1 = __builtin_amdgcn_mfma_f32_16x16x32_bf16(qf[1][ks], bfr, z1, 0, 0, 0);
                    }
                    sf[0][nt] = z0; sf[1][nt] = z1;
                }

                if (st == dst) {
                    #pragma unroll
                    for (int mt = 0; mt < 2; ++mt)
                        #pragma unroll
                        for (int nt = 0; nt < 4; ++nt)
                            #pragma unroll
                            for (int r = 0; r < 4; ++r) {
                                int qa = qt * 128 + wid * 32 + mt * 16 + quad * 4 + r;
                                int sa = st * 64 + nt * 16 + l15;
                                if (sa > qa) sf[mt][nt][r] = -INFINITY;
                            }
                }

                // p = 2^s via raw v_exp_f32; quantize round-half-up to bf16
                #pragma unroll
                for (int mt = 0; mt < 2; ++mt)
                    #pragma unroll
                    for (int nt = 0; nt < 4; ++nt)
                        #pragma unroll
                        for (int r = 0; r < 4; ++r) {
                            float p = __builtin_amdgcn_exp2f(sf[mt][nt][r]);
                            unsigned u = __builtin_bit_cast(unsigned, p) + 0x8000u;
                            Pw[(mt * 16 + quad * 4 + r) * 72 + ((nt ^ quad) * 16) + l15] =
                                (short)(u >> 16);
                        }
                // no barrier: P is wave-private

                #pragma unroll
                for (int ks = 0; ks < 2; ++ks) {
                    int blk = (ks * 2 + (quad >> 1)) ^ (l15 >> 2);
                    short8 af0 = *(const short8*)&Pw[(l15) * 72 + blk * 16 + (quad & 1) * 8];
                    short8 af1 = *(const short8*)&Pw[(16 + l15) * 72 + blk * 16 + (quad & 1) * 8];
                    lacc[0] = __builtin_amdgcn_mfma_f32_16x16x32_bf16(af0, bones, lacc[0], 0, 0, 0);
                    lacc[1] = __builtin_amdgcn_mfma_f32_16x16x32_bf16(af1, bones, lacc[1], 0, 0, 0);
                    #pragma unroll
                    for (int nt = 0; nt < 4; ++nt) {
                        short8 bfr = *(const short8*)&V0[(nt * 16 + l15) * 72 + ks * 32 + quad * 8];
                        oacc[0][nt] = __builtin_amdgcn_mfma_f32_16x16x32_bf16(af0, bfr, oacc[0][nt], 0, 0, 0);
                        oacc[1][nt] = __builtin_amdgcn_mfma_f32_16x16x32_bf16(af1, bfr, oacc[1][nt], 0, 0, 0);
                    }
                }
            }
            __syncthreads();
        }

        // lacc[mt][r] holds the full row-sum (replicated across l15)
        #pragma unroll
        for (int mt = 0; mt < 2; ++mt)
            #pragma unroll
            for (int nt = 0; nt < 4; ++nt)
                #pragma unroll
                for (int r = 0; r < 4; ++r) {
                    float v = oacc[mt][nt][r] / lacc[mt][r];
                    int qa = qt * 128 + wid * 32 + mt * 16 + quad * 4 + r;
                    O[base + (size_t)qa * 1024 + nt * 16 + l15] = f2bf(v);
                }
    }
}

// ---------------------------------------------------------------------------
// Workspace (40 MB, proven):
//   ws[ 0..16): xb (QKV-gemm input) -> Vt_g (after QKV gemm)
//   ws[16..32): Vr (QKV gemm V-plane) -> Ao (after transpose_v)
//   ws[32..38): Wall = [Wq^T*c | Wk^T | Wv^T]   ws[38..40): WoT
//   d_out: Qp (lo 16MB) + Kp (hi 16MB); overwritten by final fp32 output.
// ---------------------------------------------------------------------------
extern "C" void kernel_launch(void* const* d_in, const int* in_sizes, int n_in,
                              void* d_out, int out_size, void* d_ws, size_t ws_size,
                              hipStream_t stream) {
    const float* x  = (const float*)d_in[0];
    const float* Wq = (const float*)d_in[1];
    const float* Wk = (const float*)d_in[2];
    const float* Wv = (const float*)d_in[3];
    const float* Wo = (const float*)d_in[4];
    const float* bo = (const float*)d_in[5];
    float* out = (float*)d_out;

    char* ws = (char*)d_ws;
    const size_t MB = 1024 * 1024;
    short* xb   = (short*)(ws + 0 * MB);
    short* Vt_g = (short*)(ws + 0 * MB);    // overlays xb (dead after QKV gemm)
    short* Vr   = (short*)(ws + 16 * MB);
    short* Ao   = (short*)(ws + 16 * MB);   // overlays Vr (dead after transpose_v)
    short* Wall = (short*)(ws + 32 * MB);
    short* WoT  = (short*)(ws + 38 * MB);
    short* Qp   = (short*)d_out;            // d_out lo
    short* Kp   = Qp + 8 * 1024 * 1024;     // d_out hi

    conv_x<<<8192, 256, 0, stream>>>(x, xb);
    transpose_w<<<dim3(16, 16), 256, 0, stream>>>(Wq, Wk, Wv, Wo, Wall, WoT);

    gemm_bt<<<dim3(64, 24), 256, 0, stream>>>(xb, Wall, Qp, Vr, nullptr, nullptr,
                                              8192, 3072, 1024, 1);
    transpose_v<<<dim3(32, 16, 4), 256, 0, stream>>>(Vr, Vt_g);

    attn_fwd<<<dim3(8, 16, 4), 256, 0, stream>>>(Qp, Kp, Vt_g, Ao);

    gemm_bt<<<dim3(64, 8), 256, 0, stream>>>(Ao, WoT, nullptr, nullptr, out, bo,
                                             8192, 1024, 1024, 0);
}

// Round 11
// 279.996 us; speedup vs baseline: 1.0682x; 1.0265x over previous
//
#include <hip/hip_runtime.h>
#include <math.h>

typedef __attribute__((ext_vector_type(8))) short short8;
typedef __attribute__((ext_vector_type(4))) short short4v;
typedef __attribute__((ext_vector_type(4))) float floatx4;

#define AS1 __attribute__((address_space(1)))
#define AS3 __attribute__((address_space(3)))

__device__ inline void gload_lds16(const short* g, short* l) {
    __builtin_amdgcn_global_load_lds((const AS1 unsigned int*)g,
                                     (AS3 unsigned int*)l, 16, 0, 0);
}

__device__ inline short f2bf(float f) {
    unsigned u = __builtin_bit_cast(unsigned, f);
    u += 0x7fffu + ((u >> 16) & 1u);
    return (short)(u >> 16);
}

// ---------------------------------------------------------------------------
// x [8M] fp32 -> bf16
// ---------------------------------------------------------------------------
__global__ __launch_bounds__(256) void conv_x(
    const float* __restrict__ x, short* __restrict__ xb)
{
    int i = (blockIdx.x * 256 + threadIdx.x) * 4;
    float4 v = *(const float4*)&x[i];
    short4v o = { f2bf(v.x), f2bf(v.y), f2bf(v.z), f2bf(v.w) };
    *(short4v*)&xb[i] = o;
}

// ---------------------------------------------------------------------------
// Coalesced weight transpose + fp32->bf16 via 64x64 LDS tiles.
// Wall [3072,1024]: rows 0-1023 = Wq^T * (0.125*log2e), 1024-2047 = Wk^T,
// 2048-3071 = Wv^T.  WoT [1024,1024] = Wo^T.
// ---------------------------------------------------------------------------
__global__ __launch_bounds__(256) void transpose_w(
    const float* __restrict__ Wq, const float* __restrict__ Wk,
    const float* __restrict__ Wv, const float* __restrict__ Wo,
    short* __restrict__ Wall, short* __restrict__ WoT)
{
    __shared__ short T[64 * 72];
    const int kt = blockIdx.x, y = blockIdx.y;
    const int tid = threadIdx.x;
    const int lr = tid >> 2, lc = (tid & 3) * 16;
    #pragma unroll 1
    for (int m = 0; m < 4; ++m) {
        const float* src;
        float s = 1.f;
        if (m < 3) {
            const float* W = (m == 0) ? Wq : (m == 1) ? Wk : Wv;
            src = W + ((size_t)y << 16) + (size_t)(kt * 64 + lr) * 64 + lc;
            if (m == 0) s = 0.125f * 1.44269504088896f;   // 1/sqrt(D) * log2(e)
        } else {
            src = Wo + (size_t)(kt * 64 + lr) * 1024 + y * 64 + lc;
        }
        short8 t0, t1;
        {
            float4 v0 = *(const float4*)(src + 0);
            float4 v1 = *(const float4*)(src + 4);
            float4 v2 = *(const float4*)(src + 8);
            float4 v3 = *(const float4*)(src + 12);
            t0[0]=f2bf(v0.x*s); t0[1]=f2bf(v0.y*s); t0[2]=f2bf(v0.z*s); t0[3]=f2bf(v0.w*s);
            t0[4]=f2bf(v1.x*s); t0[5]=f2bf(v1.y*s); t0[6]=f2bf(v1.z*s); t0[7]=f2bf(v1.w*s);
            t1[0]=f2bf(v2.x*s); t1[1]=f2bf(v2.y*s); t1[2]=f2bf(v2.z*s); t1[3]=f2bf(v2.w*s);
            t1[4]=f2bf(v3.x*s); t1[5]=f2bf(v3.y*s); t1[6]=f2bf(v3.z*s); t1[7]=f2bf(v3.w*s);
        }
        *(short8*)&T[lr * 72 + lc]     = t0;
        *(short8*)&T[lr * 72 + lc + 8] = t1;
        __syncthreads();
        short8 o0, o1;
        #pragma unroll
        for (int j = 0; j < 8; ++j) o0[j] = T[(lc + j) * 72 + lr];
        #pragma unroll
        for (int j = 0; j < 8; ++j) o1[j] = T[(lc + 8 + j) * 72 + lr];
        short* dst = (m < 3)
            ? Wall + (size_t)(m * 1024 + y * 64 + lr) * 1024 + kt * 64
            : WoT  + (size_t)(y * 64 + lr) * 1024 + kt * 64;
        *(short8*)&dst[lc]     = o0;
        *(short8*)&dst[lc + 8] = o1;
        __syncthreads();
    }
}

// ---------------------------------------------------------------------------
// V [B*T, 1024] bf16 (col = h*64+d)  ->  Vt_g [b*16+h][d=64][t=2048] bf16.
// ---------------------------------------------------------------------------
__global__ __launch_bounds__(256) void transpose_v(
    const short* __restrict__ Vp, short* __restrict__ Vt_g)
{
    __shared__ short T[64 * 72];
    const int t0 = blockIdx.x * 64;
    const int h = blockIdx.y, b = blockIdx.z;
    const int tid = threadIdx.x;
    const int r = tid >> 3, c = (tid & 7) * 8;
    #pragma unroll
    for (int p = 0; p < 2; ++p) {
        int t = r + 32 * p;
        *(short8*)&T[t * 72 + c] =
            *(const short8*)&Vp[(size_t)(b * 2048 + t0 + t) * 1024 + h * 64 + c];
    }
    __syncthreads();
    const int d = tid >> 2, tc = (tid & 3) * 16;
    size_t obase = ((size_t)(b * 16 + h)) * 64 * 2048 + (size_t)d * 2048 + t0 + tc;
    short8 o0, o1;
    #pragma unroll
    for (int j = 0; j < 8; ++j) o0[j] = T[(tc + j) * 72 + d];
    #pragma unroll
    for (int j = 0; j < 8; ++j) o1[j] = T[(tc + 8 + j) * 72 + d];
    *(short8*)&Vt_g[obase] = o0;
    *(short8*)&Vt_g[obase + 8] = o1;
}

// ---------------------------------------------------------------------------
// QKV: C = A[M,K] @ BT[N,K]^T, bf16 out to planes (Q -> C, K -> C+8M, V -> Cv).
// 128x128 tile, BK=32.
// ---------------------------------------------------------------------------
__global__ __launch_bounds__(256) void gemm_bt(
    const short* __restrict__ A, const short* __restrict__ BT,
    short* __restrict__ C, short* __restrict__ Cv, int M, int N, int K)
{
    __shared__ short As[128 * 32];
    __shared__ short Bs[128 * 32];
    const int tid  = threadIdx.x;
    const int wid  = tid >> 6, lane = tid & 63;
    const int quad = lane >> 4, l15 = lane & 15;
    const int m0 = blockIdx.x * 128, n0 = blockIdx.y * 128;
    const int wr = (wid >> 1) * 64, wc = (wid & 1) * 64;

    floatx4 acc[4][4] = {};

    const int srow = wid * 32 + (lane >> 2);
    const int scol = (lane & 3) * 8;

    for (int k0 = 0; k0 < K; k0 += 32) {
        #pragma unroll
        for (int t = 0; t < 2; ++t) {
            gload_lds16(A  + (size_t)(m0 + srow + t * 16) * K + k0 + scol,
                        &As[(wid * 32 + t * 16) * 32]);
            gload_lds16(BT + (size_t)(n0 + srow + t * 16) * K + k0 + scol,
                        &Bs[(wid * 32 + t * 16) * 32]);
        }
        __syncthreads();
        short8 bfr[4];
        #pragma unroll
        for (int j = 0; j < 4; ++j)
            bfr[j] = *(const short8*)&Bs[(wc + j * 16 + l15) * 32 + quad * 8];
        #pragma unroll
        for (int i = 0; i < 4; ++i) {
            short8 afr = *(const short8*)&As[(wr + i * 16 + l15) * 32 + quad * 8];
            #pragma unroll
            for (int j = 0; j < 4; ++j)
                acc[i][j] = __builtin_amdgcn_mfma_f32_16x16x32_bf16(
                    afr, bfr[j], acc[i][j], 0, 0, 0);
        }
        __syncthreads();
    }

    #pragma unroll
    for (int i = 0; i < 4; ++i) {
        int row = m0 + wr + i * 16 + quad * 4;
        #pragma unroll
        for (int j = 0; j < 4; ++j) {
            int col = n0 + wc + j * 16 + l15;
            int plane = col >> 10, c1 = col & 1023;
            short* dst = (plane == 2) ? Cv : C + (size_t)plane * 8192 * 1024;
            #pragma unroll
            for (int r = 0; r < 4; ++r)
                dst[(size_t)(row + r) * 1024 + c1] = f2bf(acc[i][j][r]);
        }
    }
}

// ---------------------------------------------------------------------------
// O-projection GEMM: 64x128 tile (grid 128x8 = 1024 blocks -> 4 blocks/CU;
// the 128x128 tile would cap at 512 blocks = 2/CU for N=1024).
// fp32 output + bias.
// ---------------------------------------------------------------------------
__global__ __launch_bounds__(256) void gemm_o(
    const short* __restrict__ A, const short* __restrict__ BT,
    float* __restrict__ Cf, const float* __restrict__ bias, int N, int K)
{
    __shared__ short As[64 * 32];
    __shared__ short Bs[128 * 32];
    const int tid  = threadIdx.x;
    const int wid  = tid >> 6, lane = tid & 63;
    const int quad = lane >> 4, l15 = lane & 15;
    const int m0 = blockIdx.x * 64, n0 = blockIdx.y * 128;
    const int wr = (wid >> 1) * 32, wc = (wid & 1) * 64;

    floatx4 acc[2][4] = {};

    const int arow = tid >> 2, acol = (tid & 3) * 8;          // 64 rows x 4 chunks
    const int brow = wid * 32 + (lane >> 2), bcol = (lane & 3) * 8;

    for (int k0 = 0; k0 < K; k0 += 32) {
        gload_lds16(A + (size_t)(m0 + arow) * K + k0 + acol, &As[(wid * 16) * 32]);
        #pragma unroll
        for (int t = 0; t < 2; ++t)
            gload_lds16(BT + (size_t)(n0 + brow + t * 16) * K + k0 + bcol,
                        &Bs[(wid * 32 + t * 16) * 32]);
        __syncthreads();
        short8 bfr[4];
        #pragma unroll
        for (int j = 0; j < 4; ++j)
            bfr[j] = *(const short8*)&Bs[(wc + j * 16 + l15) * 32 + quad * 8];
        #pragma unroll
        for (int i = 0; i < 2; ++i) {
            short8 afr = *(const short8*)&As[(wr + i * 16 + l15) * 32 + quad * 8];
            #pragma unroll
            for (int j = 0; j < 4; ++j)
                acc[i][j] = __builtin_amdgcn_mfma_f32_16x16x32_bf16(
                    afr, bfr[j], acc[i][j], 0, 0, 0);
        }
        __syncthreads();
    }

    #pragma unroll
    for (int i = 0; i < 2; ++i) {
        int row = m0 + wr + i * 16 + quad * 4;
        #pragma unroll
        for (int j = 0; j < 4; ++j) {
            int col = n0 + wc + j * 16 + l15;
            float bv = bias[col];
            #pragma unroll
            for (int r = 0; r < 4; ++r)
                Cf[(size_t)(row + r) * N + col] = acc[i][j][r] + bv;
        }
    }
}

// ---------------------------------------------------------------------------
// Flash attention, causal, non-online softmax. Q pre-scaled by log2e/sqrt(D);
// exp via raw v_exp_f32. Row-sums l via ones-MFMA. P quantize = truncation
// (consistent numerator/denominator).
// K/V staged by global_load_lds (no VGPR round-trip, no ds_writes) into
// XOR-swizzled unpadded tiles: LDS chunk c' = c ^ (row&7); fragment reads
// undo the swizzle -> conflict-free (8 lanes per 4-bank group over 4-cyc
// b128). Double-buffered; the compiler's vmcnt(0)-before-barrier drains the
// next tile's loads exactly at the single end-of-iter barrier.
// Block = 128 q-rows, 4 waves x 32 rows. Grid (8,H,B): block pi does q-tiles
// {15-pi, pi} -> uniform 34 s-iters.
// ---------------------------------------------------------------------------
__global__ __launch_bounds__(256) void attn_fwd(
    const short* __restrict__ Q, const short* __restrict__ Kg,
    const short* __restrict__ Vt_g, short* __restrict__ O)
{
    __shared__ short Ks[2][64 * 64];
    __shared__ short Vs[2][64 * 64];
    __shared__ short Pb[4 * 32 * 72];
    const int tid  = threadIdx.x;
    const int wid  = tid >> 6, lane = tid & 63;
    const int quad = lane >> 4, l15 = lane & 15;
    const int pi = blockIdx.x, h = blockIdx.y, b = blockIdx.z;
    const size_t base  = ((size_t)b * 2048) * 1024 + h * 64;
    const size_t vbase = ((size_t)(b * 16 + h)) * 64 * 2048;
    short* Pw = &Pb[wid * 32 * 72];

    // staging: thread covers rows {srow, srow+32}; global chunk XOR-swizzled
    const int srow = tid >> 3;                         // 0..31
    const int gcol = ((tid & 7) ^ (srow & 7)) * 8;     // (srow+32)&7 == srow&7
    const int lbase0 = (wid * 8) * 64;                 // wave-uniform LDS bases
    const int lbase1 = (wid * 8 + 32) * 64;
    const int l7 = l15 & 7;

    const short one_bf = (short)0x3F80;                // bf16 1.0
    const short8 bones = { one_bf, one_bf, one_bf, one_bf,
                           one_bf, one_bf, one_bf, one_bf };

    for (int ph = 0; ph < 2; ++ph) {
        const int qt = ph ? pi : 15 - pi;
        short8 qf[2][2];
        #pragma unroll
        for (int mt = 0; mt < 2; ++mt)
            #pragma unroll
            for (int ks = 0; ks < 2; ++ks)
                qf[mt][ks] = *(const short8*)&Q[base +
                    (size_t)(qt * 128 + wid * 32 + mt * 16 + l15) * 1024 + ks * 32 + quad * 8];

        floatx4 oacc[2][4] = {};
        floatx4 lacc[2] = {};
        const int dst = 2 * qt + (wid >> 1);
        const int nst = 2 * qt + 2;

        const short* kptr = Kg + base + (size_t)srow * 1024 + gcol;
        const short* vptr = Vt_g + vbase + (size_t)srow * 2048 + gcol;

        // prologue: issue tile 0 into buf 0
        gload_lds16(kptr,               &Ks[0][lbase0]);
        gload_lds16(kptr + 32 * 1024,   &Ks[0][lbase1]);
        gload_lds16(vptr,               &Vs[0][lbase0]);
        gload_lds16(vptr + 32 * 2048,   &Vs[0][lbase1]);
        kptr += 64 * 1024; vptr += 64;
        __syncthreads();

        for (int st = 0; st < nst; ++st) {
            const short* K0 = Ks[st & 1];
            const short* V0 = Vs[st & 1];
            if (st + 1 < nst) {
                short* K1 = Ks[(st + 1) & 1];
                short* V1 = Vs[(st + 1) & 1];
                gload_lds16(kptr,             &K1[lbase0]);
                gload_lds16(kptr + 32 * 1024, &K1[lbase1]);
                gload_lds16(vptr,             &V1[lbase0]);
                gload_lds16(vptr + 32 * 2048, &V1[lbase1]);
                kptr += 64 * 1024; vptr += 64;
            }

            if (st <= dst) {
                floatx4 sf[2][4];
                #pragma unroll
                for (int nt = 0; nt < 4; ++nt) {
                    floatx4 z0 = {}, z1 = {};
                    #pragma unroll
                    for (int ks = 0; ks < 2; ++ks) {
                        short8 bfr = *(const short8*)&K0[(nt * 16 + l15) * 64 +
                                                         (((ks * 4 + quad) ^ l7) * 8)];
                        z0 = __builtin_amdgcn_mfma_f32_16x16x32_bf16(qf[0][ks], bfr, z0, 0, 0, 0);
                        z1 = __builtin_amdgcn_mfma_f32_16x16x32_bf16(qf[1][ks], bfr, z1, 0, 0, 0);
                    }
                    sf[0][nt] = z0; sf[1][nt] = z1;
                }

                if (st == dst) {
                    #pragma unroll
                    for (int mt = 0; mt < 2; ++mt)
                        #pragma unroll
                        for (int nt = 0; nt < 4; ++nt)
                            #pragma unroll
                            for (int r = 0; r < 4; ++r) {
                                int qa = qt * 128 + wid * 32 + mt * 16 + quad * 4 + r;
                                int sa = st * 64 + nt * 16 + l15;
                                if (sa > qa) sf[mt][nt][r] = -INFINITY;
                            }
                }

                // p = 2^s via raw v_exp_f32; truncate to bf16 (consistent
                // numerator/denominator -> pure weight perturbation)
                #pragma unroll
                for (int mt = 0; mt < 2; ++mt)
                    #pragma unroll
                    for (int nt = 0; nt < 4; ++nt)
                        #pragma unroll
                        for (int r = 0; r < 4; ++r) {
                            float p = __builtin_amdgcn_exp2f(sf[mt][nt][r]);
                            unsigned u = __builtin_bit_cast(unsigned, p);
                            Pw[(mt * 16 + quad * 4 + r) * 72 + ((nt ^ quad) * 16) + l15] =
                                (short)(u >> 16);
                        }
                // no barrier: P is wave-private

                #pragma unroll
                for (int ks = 0; ks < 2; ++ks) {
                    int blk = (ks * 2 + (quad >> 1)) ^ (l15 >> 2);
                    short8 af0 = *(const short8*)&Pw[(l15) * 72 + blk * 16 + (quad & 1) * 8];
                    short8 af1 = *(const short8*)&Pw[(16 + l15) * 72 + blk * 16 + (quad & 1) * 8];
                    lacc[0] = __builtin_amdgcn_mfma_f32_16x16x32_bf16(af0, bones, lacc[0], 0, 0, 0);
                    lacc[1] = __builtin_amdgcn_mfma_f32_16x16x32_bf16(af1, bones, lacc[1], 0, 0, 0);
                    #pragma unroll
                    for (int nt = 0; nt < 4; ++nt) {
                        short8 bfr = *(const short8*)&V0[(nt * 16 + l15) * 64 +
                                                         (((ks * 4 + quad) ^ l7) * 8)];
                        oacc[0][nt] = __builtin_amdgcn_mfma_f32_16x16x32_bf16(af0, bfr, oacc[0][nt], 0, 0, 0);
                        oacc[1][nt] = __builtin_amdgcn_mfma_f32_16x16x32_bf16(af1, bfr, oacc[1][nt], 0, 0, 0);
                    }
                }
            }
            __syncthreads();   // drains next tile's global_load_lds too
        }

        // lacc[mt][r] holds the full row-sum (replicated across l15)
        #pragma unroll
        for (int mt = 0; mt < 2; ++mt)
            #pragma unroll
            for (int nt = 0; nt < 4; ++nt)
                #pragma unroll
                for (int r = 0; r < 4; ++r) {
                    float v = oacc[mt][nt][r] / lacc[mt][r];
                    int qa = qt * 128 + wid * 32 + mt * 16 + quad * 4 + r;
                    O[base + (size_t)qa * 1024 + nt * 16 + l15] = f2bf(v);
                }
    }
}

// ---------------------------------------------------------------------------
// Workspace (40 MB, proven):
//   ws[ 0..16): xb (QKV-gemm input) -> Vt_g (after QKV gemm)
//   ws[16..32): Vr (QKV gemm V-plane) -> Ao (after transpose_v)
//   ws[32..38): Wall = [Wq^T*c | Wk^T | Wv^T]   ws[38..40): WoT
//   d_out: Qp (lo 16MB) + Kp (hi 16MB); overwritten by final fp32 output.
// ---------------------------------------------------------------------------
extern "C" void kernel_launch(void* const* d_in, const int* in_sizes, int n_in,
                              void* d_out, int out_size, void* d_ws, size_t ws_size,
                              hipStream_t stream) {
    const float* x  = (const float*)d_in[0];
    const float* Wq = (const float*)d_in[1];
    const float* Wk = (const float*)d_in[2];
    const float* Wv = (const float*)d_in[3];
    const float* Wo = (const float*)d_in[4];
    const float* bo = (const float*)d_in[5];
    float* out = (float*)d_out;

    char* ws = (char*)d_ws;
    const size_t MB = 1024 * 1024;
    short* xb   = (short*)(ws + 0 * MB);
    short* Vt_g = (short*)(ws + 0 * MB);    // overlays xb (dead after QKV gemm)
    short* Vr   = (short*)(ws + 16 * MB);
    short* Ao   = (short*)(ws + 16 * MB);   // overlays Vr (dead after transpose_v)
    short* Wall = (short*)(ws + 32 * MB);
    short* WoT  = (short*)(ws + 38 * MB);
    short* Qp   = (short*)d_out;            // d_out lo
    short* Kp   = Qp + 8 * 1024 * 1024;     // d_out hi

    conv_x<<<8192, 256, 0, stream>>>(x, xb);
    transpose_w<<<dim3(16, 16), 256, 0, stream>>>(Wq, Wk, Wv, Wo, Wall, WoT);

    gemm_bt<<<dim3(64, 24), 256, 0, stream>>>(xb, Wall, Qp, Vr, 8192, 3072, 1024);
    transpose_v<<<dim3(32, 16, 4), 256, 0, stream>>>(Vr, Vt_g);

    attn_fwd<<<dim3(8, 16, 4), 256, 0, stream>>>(Qp, Kp, Vt_g, Ao);

    gemm_o<<<dim3(128, 8), 256, 0, stream>>>(Ao, WoT, out, bo, 1024, 1024);
}